// Round 14
// baseline (89.990 us; speedup 1.0000x reference)
//
#include <hip/hip_runtime.h>
#include <math.h>

#define BB 32
#define CC 256
#define HWW 4096

typedef unsigned short u16;
typedef unsigned int u32;

typedef __attribute__((ext_vector_type(8))) short bf16x8;
typedef __attribute__((ext_vector_type(4))) float f32x4;

__device__ inline u16 f2bf(float f) {
    u32 u = __float_as_uint(f);
    u32 r = (u + 0x7fff + ((u >> 16) & 1)) >> 16;   // RNE
    return (u16)r;
}

// ========== Kernel A: avg-pool partials + transpose x -> xT[b][n][k] bf16 ==========
// x is dead after this kernel: NT (streaming) loads keep it from evicting xT/out in L3.

__global__ __launch_bounds__(256) void pool_transpose_kernel(const float* __restrict__ x,
                                                             u16* __restrict__ xT,
                                                             float* __restrict__ partial) {
    int b  = blockIdx.z;
    int c0 = blockIdx.y * 64;
    int h0 = blockIdx.x * 64;
    const float* xB = x + (size_t)b * CC * HWW;

    __shared__ float tile[64][65];
    __shared__ float psum[64];
    int t  = threadIdx.x;
    int cl = t >> 4;            // 0..15
    int h4 = (t & 15) * 4;

#pragma unroll
    for (int m = 0; m < 4; ++m) {
        int c = cl + 16 * m;
        f32x4 v = __builtin_nontemporal_load((const f32x4*)&xB[(size_t)(c0 + c) * HWW + h0 + h4]);
        tile[c][h4 + 0] = v[0];
        tile[c][h4 + 1] = v[1];
        tile[c][h4 + 2] = v[2];
        tile[c][h4 + 3] = v[3];
        float s = v[0] + v[1] + v[2] + v[3];
#pragma unroll
        for (int off = 8; off > 0; off >>= 1)
            s += __shfl_down(s, off, 16);
        if ((t & 15) == 0) psum[c] = s;
    }
    __syncthreads();

    if (t < 64)
        partial[((size_t)b * 64 + blockIdx.x) * CC + c0 + t] = psum[t];

    int hl = t >> 2;            // 0..63
    int cq = (t & 3) * 16;      // 0,16,32,48
    u32 p0 = (u32)f2bf(tile[cq + 0][hl]) | ((u32)f2bf(tile[cq + 1][hl]) << 16);
    u32 p1 = (u32)f2bf(tile[cq + 2][hl]) | ((u32)f2bf(tile[cq + 3][hl]) << 16);
    u32 p2 = (u32)f2bf(tile[cq + 4][hl]) | ((u32)f2bf(tile[cq + 5][hl]) << 16);
    u32 p3 = (u32)f2bf(tile[cq + 6][hl]) | ((u32)f2bf(tile[cq + 7][hl]) << 16);
    u32 p4 = (u32)f2bf(tile[cq + 8][hl]) | ((u32)f2bf(tile[cq + 9][hl]) << 16);
    u32 p5 = (u32)f2bf(tile[cq +10][hl]) | ((u32)f2bf(tile[cq +11][hl]) << 16);
    u32 p6 = (u32)f2bf(tile[cq +12][hl]) | ((u32)f2bf(tile[cq +13][hl]) << 16);
    u32 p7 = (u32)f2bf(tile[cq +14][hl]) | ((u32)f2bf(tile[cq +15][hl]) << 16);
    u16* dst = xT + ((size_t)b * HWW + h0 + hl) * CC + c0 + cq;
    *(uint4*)(dst)     = make_uint4(p0, p1, p2, p3);
    *(uint4*)(dst + 8) = make_uint4(p4, p5, p6, p7);
}

// ========== Kernel B: fused reduce + weight ==========

__global__ __launch_bounds__(256) void reduce_weight_kernel(const float* __restrict__ partial,
                                                            const float* __restrict__ adj,
                                                            u16* __restrict__ wb) {
    int b  = blockIdx.x >> 3;
    int ic = (blockIdx.x & 7) * 32;
    int t  = threadIdx.x;

    __shared__ float ca[CC];
    float s = 0.f;
#pragma unroll 8
    for (int hx = 0; hx < 64; ++hx)
        s += partial[((size_t)b * 64 + hx) * CC + t];
    ca[t] = s * (1.0f / HWW);
    __syncthreads();

    u16* wB = wb + (size_t)b * CC * CC;
    float cj = ca[t];
#pragma unroll 4
    for (int r = 0; r < 32; ++r) {
        int i = ic + r;
        float d  = cj - ca[i];
        float tt = __expf(-fabsf(d));
        float sv = 2.f * tt / (1.f + tt);
        wB[(size_t)i * CC + t] = f2bf(adj[i * CC + t] * sv);
    }
}

// ========== Kernel C: MFMA GEMM + para + relu (R12-verified) ==========
// 3-buffer pipeline, counted vmcnt. Ledger: after STAGE at kt, outstanding =
// {stage kt+1 (4), stage kt+2 (4)}. vmcnt(4) retires stage kt+1. At kt>=6 no
// new STAGE -> drain to vmcnt(0) before consuming stage 7.
#define GBM 128
#define GBN 128
#define GBK 32

__global__ __launch_bounds__(256) void mfma_gemm_kernel(const u16* __restrict__ wb,
                                                        const u16* __restrict__ xT,
                                                        const float* __restrict__ para,
                                                        float* __restrict__ out) {
    int b  = blockIdx.z;
    int i0 = blockIdx.y * GBM;
    int n0 = blockIdx.x * GBN;
    const u16* wB = wb + (size_t)b * CC * CC;     // [i][k], k contiguous
    const u16* xB = xT + (size_t)b * HWW * CC;    // [n][k], k contiguous

    __shared__ u16 lds[3][2][4096];               // 48KB; epilogue reuses first 32KB

    int t    = threadIdx.x;
    int lane = t & 63;
    int wid  = t >> 6;
    int wid_s = __builtin_amdgcn_readfirstlane(wid);
    int wr   = wid >> 1;
    int wc   = wid & 1;

    f32x4 acc[4][4] = {};

    int r0  = t >> 2;
    int c0q = t & 3;
    int csq = c0q ^ ((r0 >> 1) & 3);              // pre-swizzled GLOBAL chunk

    const u16* gA0 = wB + (size_t)(i0 + r0) * CC + 8 * csq;
    const u16* gA1 = wB + (size_t)(i0 + r0 + 64) * CC + 8 * csq;
    const u16* gB0 = xB + (size_t)(n0 + r0) * CC + 8 * csq;
    const u16* gB1 = xB + (size_t)(n0 + r0 + 64) * CC + 8 * csq;

#define GLDS(ptr, dst) __builtin_amdgcn_global_load_lds( \
        (const __attribute__((address_space(1))) void*)(ptr), \
        (__attribute__((address_space(3))) void*)(dst), 16, 0, 0)

#define STAGE(kk, bf) { \
        GLDS(gA0 + (kk), &lds[bf][0][wid_s * 512]); \
        GLDS(gA1 + (kk), &lds[bf][0][2048 + wid_s * 512]); \
        GLDS(gB0 + (kk), &lds[bf][1][wid_s * 512]); \
        GLDS(gB1 + (kk), &lds[bf][1][2048 + wid_s * 512]); }

    STAGE(0, 0);
    STAGE(GBK, 1);
    asm volatile("s_waitcnt vmcnt(4)" ::: "memory");
    __builtin_amdgcn_s_barrier();

    int lrow = lane & 15;
    int kc   = lane >> 4;
    int swz  = (lrow >> 1) & 3;

    int cur = 0;
#pragma unroll 1
    for (int kt = 0; kt < 8; ++kt) {
        if (kt < 6) {
            int nxt = cur + 2; if (nxt >= 3) nxt -= 3;
            STAGE((kt + 2) * GBK, nxt);
        }

        bf16x8 af[4], bfr[4];
#pragma unroll
        for (int m = 0; m < 4; ++m) {
            int row = wr * 64 + m * 16 + lrow;
            af[m] = *(bf16x8*)&lds[cur][0][row * 32 + 8 * (kc ^ swz)];
        }
#pragma unroll
        for (int q = 0; q < 4; ++q) {
            int row = wc * 64 + q * 16 + lrow;
            bfr[q] = *(bf16x8*)&lds[cur][1][row * 32 + 8 * (kc ^ swz)];
        }
#pragma unroll
        for (int m = 0; m < 4; ++m)
#pragma unroll
            for (int q = 0; q < 4; ++q)
                acc[m][q] = __builtin_amdgcn_mfma_f32_16x16x32_bf16(af[m], bfr[q], acc[m][q], 0, 0, 0);

        if (kt < 6) {
            asm volatile("s_waitcnt vmcnt(4)" ::: "memory");
        } else {
            asm volatile("s_waitcnt vmcnt(0)" ::: "memory");
        }
        __builtin_amdgcn_s_barrier();
        cur = (cur + 1 == 3) ? 0 : cur + 1;
    }
#undef STAGE
#undef GLDS

    // ---- epilogue: wave-private LDS transpose -> fully-coalesced NT dwordx4 ----
    float* sl = (float*)&lds[0][0][0] + wid * 2048;
#pragma unroll
    for (int h = 0; h < 2; ++h) {
#pragma unroll
        for (int m2 = 0; m2 < 2; ++m2) {
#pragma unroll
            for (int q = 0; q < 4; ++q) {
#pragma unroll
                for (int r = 0; r < 4; ++r) {
                    int i_loc = m2 * 16 + 4 * kc + r;
                    int n_swz = (q * 16 + lrow) ^ (((i_loc >> 2) & 3) << 4);
                    sl[i_loc * 64 + n_swz] = acc[2 * h + m2][q][r];
                }
            }
        }
#pragma unroll
        for (int j = 0; j < 8; ++j) {
            int i_loc = j * 4 + kc;
            int nb    = lrow * 4;
            int n_swz = nb ^ (((i_loc >> 2) & 3) << 4);
            f32x4 v  = *(f32x4*)&sl[i_loc * 64 + n_swz];
            int gi = i0 + wr * 64 + h * 32 + i_loc;
            int gn = n0 + wc * 64 + nb;
            f32x4 pv = *(const f32x4*)&para[(size_t)gi * HWW + gn];
            f32x4 o;
            o[0] = fmaxf(v[0] * pv[0], 0.f);
            o[1] = fmaxf(v[1] * pv[1], 0.f);
            o[2] = fmaxf(v[2] * pv[2], 0.f);
            o[3] = fmaxf(v[3] * pv[3], 0.f);
            __builtin_nontemporal_store(o, (f32x4*)&out[((size_t)b * CC + gi) * HWW + gn]);
        }
    }
}

// ================= FALLBACK (fp32 path, used if ws too small) =================

__global__ __launch_bounds__(256) void avgpool_kernel(const float* __restrict__ x,
                                                      float* __restrict__ c_adj) {
    int bc = blockIdx.x;
    const float4* p4 = (const float4*)(x + (size_t)bc * HWW);
    int t = threadIdx.x;
    float sum = 0.f;
#pragma unroll
    for (int m = 0; m < 4; ++m) {
        float4 v = p4[t + 256 * m];
        sum += v.x + v.y + v.z + v.w;
    }
#pragma unroll
    for (int off = 32; off > 0; off >>= 1)
        sum += __shfl_down(sum, off, 64);
    __shared__ float partial[4];
    int wid = t >> 6, lane = t & 63;
    if (lane == 0) partial[wid] = sum;
    __syncthreads();
    if (t == 0)
        c_adj[bc] = (partial[0] + partial[1] + partial[2] + partial[3]) * (1.0f / HWW);
}

__global__ __launch_bounds__(256) void weight_kernel(const float* __restrict__ c_adj,
                                                     const float* __restrict__ adj,
                                                     float* __restrict__ w) {
    int idx = blockIdx.x * 256 + threadIdx.x;
    int b = idx >> 16, rem = idx & 65535, i = rem >> 8, j = rem & 255;
    float d = c_adj[b * CC + j] - c_adj[b * CC + i];
    float tt = expf(-fabsf(d));
    w[idx] = adj[i * CC + j] * 2.f * tt / (1.f + tt);
}

#define BM 64
#define BN 64
#define BK 16
__global__ __launch_bounds__(256) void gemm_kernel(const float* __restrict__ w,
                                                   const float* __restrict__ x,
                                                   const float* __restrict__ para,
                                                   float* __restrict__ out) {
    int b = blockIdx.z, i0 = blockIdx.y * BM, n0 = blockIdx.x * BN;
    const float* wB = w + (size_t)b * CC * CC;
    const float* xB = x + (size_t)b * CC * HWW;
    float* outB = out + (size_t)b * CC * HWW;
    __shared__ float wT[BK][68];
    __shared__ float xS[BK][BN];
    int t = threadIdx.x, tr = t >> 4, tc = t & 15;
    float acc[4][4] = {};
    for (int k0 = 0; k0 < CC; k0 += BK) {
        {
            int i = t >> 2, kq = (t & 3) * 4;
            float4 v = *(const float4*)&wB[(size_t)(i0 + i) * CC + k0 + kq];
            wT[kq + 0][i] = v.x; wT[kq + 1][i] = v.y; wT[kq + 2][i] = v.z; wT[kq + 3][i] = v.w;
        }
        {
            int k = t >> 4, nq = (t & 15) * 4;
            *(float4*)&xS[k][nq] = *(const float4*)&xB[(size_t)(k0 + k) * HWW + n0 + nq];
        }
        __syncthreads();
#pragma unroll
        for (int k = 0; k < BK; ++k) {
            float wv[4], xv[4];
            *(float4*)wv = *(const float4*)&wT[k][tr * 4];
            *(float4*)xv = *(const float4*)&xS[k][tc * 4];
#pragma unroll
            for (int r = 0; r < 4; ++r)
#pragma unroll
                for (int q = 0; q < 4; ++q)
                    acc[r][q] = fmaf(wv[r], xv[q], acc[r][q]);
        }
        __syncthreads();
    }
#pragma unroll
    for (int r = 0; r < 4; ++r) {
        int i = i0 + tr * 4 + r, n = n0 + tc * 4;
        float4 pv = *(const float4*)&para[(size_t)i * HWW + n];
        float4 o;
        o.x = fmaxf(acc[r][0] * pv.x, 0.f);
        o.y = fmaxf(acc[r][1] * pv.y, 0.f);
        o.z = fmaxf(acc[r][2] * pv.z, 0.f);
        o.w = fmaxf(acc[r][3] * pv.w, 0.f);
        *(float4*)&outB[(size_t)i * HWW + n] = o;
    }
}

// ================= launch =================

extern "C" void kernel_launch(void* const* d_in, const int* in_sizes, int n_in,
                              void* d_out, int out_size, void* d_ws, size_t ws_size,
                              hipStream_t stream) {
    const float* x    = (const float*)d_in[0];
    const float* adj  = (const float*)d_in[1];
    const float* para = (const float*)d_in[2];
    float* out = (float*)d_out;

    const size_t XT_BYTES = (size_t)BB * HWW * CC * 2;       // 67,108,864
    const size_t WB_BYTES = (size_t)BB * CC * CC * 2;        //  4,194,304
    const size_t PT_BYTES = (size_t)BB * 64 * CC * 4;        //  2,097,152
    const size_t REQ = XT_BYTES + WB_BYTES + PT_BYTES;

    if (ws_size >= REQ) {
        u16*   xT      = (u16*)d_ws;
        u16*   wbuf    = (u16*)((char*)d_ws + XT_BYTES);
        float* partial = (float*)((char*)d_ws + XT_BYTES + WB_BYTES);

        dim3 gA(HWW / 64, CC / 64, BB);
        pool_transpose_kernel<<<gA, 256, 0, stream>>>(x, xT, partial);
        reduce_weight_kernel<<<BB * 8, 256, 0, stream>>>(partial, adj, wbuf);
        dim3 gC(HWW / GBN, CC / GBM, BB);
        mfma_gemm_kernel<<<gC, 256, 0, stream>>>(wbuf, xT, para, out);
    } else {
        float* c_adj = (float*)d_ws;
        float* w     = (float*)d_ws + (BB * CC);
        avgpool_kernel<<<BB * CC, 256, 0, stream>>>(x, c_adj);
        weight_kernel<<<(BB * CC * CC) / 256, 256, 0, stream>>>(c_adj, adj, w);
        dim3 grid(HWW / BN, CC / BM, BB);
        gemm_kernel<<<grid, 256, 0, stream>>>(w, x, para, out);
    }
}

// Round 15
// 83.379 us; speedup vs baseline: 1.0793x; 1.0793x over previous
//
#include <hip/hip_runtime.h>
#include <math.h>

#define BB 32
#define CC 256
#define HWW 4096

typedef unsigned short u16;
typedef unsigned int u32;

typedef __attribute__((ext_vector_type(8))) short bf16x8;
typedef __attribute__((ext_vector_type(4))) float f32x4;

__device__ inline u16 f2bf(float f) {
    u32 u = __float_as_uint(f);
    u32 r = (u + 0x7fff + ((u >> 16) & 1)) >> 16;   // RNE
    return (u16)r;
}

// ========== Kernel A: avg-pool partials + transpose x -> xT[b][n][k] bf16 ==========

__global__ __launch_bounds__(256) void pool_transpose_kernel(const float* __restrict__ x,
                                                             u16* __restrict__ xT,
                                                             float* __restrict__ partial) {
    int b  = blockIdx.z;
    int c0 = blockIdx.y * 64;
    int h0 = blockIdx.x * 64;
    const float* xB = x + (size_t)b * CC * HWW;

    __shared__ float tile[64][65];
    __shared__ float psum[64];
    int t  = threadIdx.x;
    int cl = t >> 4;            // 0..15
    int h4 = (t & 15) * 4;

#pragma unroll
    for (int m = 0; m < 4; ++m) {
        int c = cl + 16 * m;
        float4 v = *(const float4*)&xB[(size_t)(c0 + c) * HWW + h0 + h4];
        tile[c][h4 + 0] = v.x;
        tile[c][h4 + 1] = v.y;
        tile[c][h4 + 2] = v.z;
        tile[c][h4 + 3] = v.w;
        float s = v.x + v.y + v.z + v.w;
#pragma unroll
        for (int off = 8; off > 0; off >>= 1)
            s += __shfl_down(s, off, 16);
        if ((t & 15) == 0) psum[c] = s;
    }
    __syncthreads();

    if (t < 64)
        partial[((size_t)b * 64 + blockIdx.x) * CC + c0 + t] = psum[t];

    int hl = t >> 2;            // 0..63
    int cq = (t & 3) * 16;      // 0,16,32,48
    u32 p0 = (u32)f2bf(tile[cq + 0][hl]) | ((u32)f2bf(tile[cq + 1][hl]) << 16);
    u32 p1 = (u32)f2bf(tile[cq + 2][hl]) | ((u32)f2bf(tile[cq + 3][hl]) << 16);
    u32 p2 = (u32)f2bf(tile[cq + 4][hl]) | ((u32)f2bf(tile[cq + 5][hl]) << 16);
    u32 p3 = (u32)f2bf(tile[cq + 6][hl]) | ((u32)f2bf(tile[cq + 7][hl]) << 16);
    u32 p4 = (u32)f2bf(tile[cq + 8][hl]) | ((u32)f2bf(tile[cq + 9][hl]) << 16);
    u32 p5 = (u32)f2bf(tile[cq +10][hl]) | ((u32)f2bf(tile[cq +11][hl]) << 16);
    u32 p6 = (u32)f2bf(tile[cq +12][hl]) | ((u32)f2bf(tile[cq +13][hl]) << 16);
    u32 p7 = (u32)f2bf(tile[cq +14][hl]) | ((u32)f2bf(tile[cq +15][hl]) << 16);
    u16* dst = xT + ((size_t)b * HWW + h0 + hl) * CC + c0 + cq;
    *(uint4*)(dst)     = make_uint4(p0, p1, p2, p3);
    *(uint4*)(dst + 8) = make_uint4(p4, p5, p6, p7);
}

// ========== Kernel B: fused reduce + weight ==========

__global__ __launch_bounds__(256) void reduce_weight_kernel(const float* __restrict__ partial,
                                                            const float* __restrict__ adj,
                                                            u16* __restrict__ wb) {
    int b  = blockIdx.x >> 3;
    int ic = (blockIdx.x & 7) * 32;
    int t  = threadIdx.x;

    __shared__ float ca[CC];
    float s = 0.f;
#pragma unroll 8
    for (int hx = 0; hx < 64; ++hx)
        s += partial[((size_t)b * 64 + hx) * CC + t];
    ca[t] = s * (1.0f / HWW);
    __syncthreads();

    u16* wB = wb + (size_t)b * CC * CC;
    float cj = ca[t];
#pragma unroll 4
    for (int r = 0; r < 32; ++r) {
        int i = ic + r;
        float d  = cj - ca[i];
        float tt = __expf(-fabsf(d));
        float sv = 2.f * tt / (1.f + tt);
        wB[(size_t)i * CC + t] = f2bf(adj[i * CC + t] * sv);
    }
}

// ========== Kernel C: MFMA GEMM + para + relu (R12-verified) ==========
// 3-buffer pipeline, counted vmcnt. Ledger: after STAGE at kt, outstanding =
// {stage kt+1 (4), stage kt+2 (4)}. vmcnt(4) retires stage kt+1. At kt>=6 no
// new STAGE -> drain to vmcnt(0) before consuming stage 7.
#define GBM 128
#define GBN 128
#define GBK 32

__global__ __launch_bounds__(256) void mfma_gemm_kernel(const u16* __restrict__ wb,
                                                        const u16* __restrict__ xT,
                                                        const float* __restrict__ para,
                                                        float* __restrict__ out) {
    int b  = blockIdx.z;
    int i0 = blockIdx.y * GBM;
    int n0 = blockIdx.x * GBN;
    const u16* wB = wb + (size_t)b * CC * CC;     // [i][k], k contiguous
    const u16* xB = xT + (size_t)b * HWW * CC;    // [n][k], k contiguous

    __shared__ u16 lds[3][2][4096];               // 48KB; epilogue reuses first 32KB

    int t    = threadIdx.x;
    int lane = t & 63;
    int wid  = t >> 6;
    int wid_s = __builtin_amdgcn_readfirstlane(wid);
    int wr   = wid >> 1;
    int wc   = wid & 1;

    f32x4 acc[4][4] = {};

    int r0  = t >> 2;
    int c0q = t & 3;
    int csq = c0q ^ ((r0 >> 1) & 3);              // pre-swizzled GLOBAL chunk

    const u16* gA0 = wB + (size_t)(i0 + r0) * CC + 8 * csq;
    const u16* gA1 = wB + (size_t)(i0 + r0 + 64) * CC + 8 * csq;
    const u16* gB0 = xB + (size_t)(n0 + r0) * CC + 8 * csq;
    const u16* gB1 = xB + (size_t)(n0 + r0 + 64) * CC + 8 * csq;

#define GLDS(ptr, dst) __builtin_amdgcn_global_load_lds( \
        (const __attribute__((address_space(1))) void*)(ptr), \
        (__attribute__((address_space(3))) void*)(dst), 16, 0, 0)

#define STAGE(kk, bf) { \
        GLDS(gA0 + (kk), &lds[bf][0][wid_s * 512]); \
        GLDS(gA1 + (kk), &lds[bf][0][2048 + wid_s * 512]); \
        GLDS(gB0 + (kk), &lds[bf][1][wid_s * 512]); \
        GLDS(gB1 + (kk), &lds[bf][1][2048 + wid_s * 512]); }

    STAGE(0, 0);
    STAGE(GBK, 1);
    asm volatile("s_waitcnt vmcnt(4)" ::: "memory");
    __builtin_amdgcn_s_barrier();

    int lrow = lane & 15;
    int kc   = lane >> 4;
    int swz  = (lrow >> 1) & 3;

    int cur = 0;
#pragma unroll 1
    for (int kt = 0; kt < 8; ++kt) {
        if (kt < 6) {
            int nxt = cur + 2; if (nxt >= 3) nxt -= 3;
            STAGE((kt + 2) * GBK, nxt);
        }

        bf16x8 af[4], bfr[4];
#pragma unroll
        for (int m = 0; m < 4; ++m) {
            int row = wr * 64 + m * 16 + lrow;
            af[m] = *(bf16x8*)&lds[cur][0][row * 32 + 8 * (kc ^ swz)];
        }
#pragma unroll
        for (int q = 0; q < 4; ++q) {
            int row = wc * 64 + q * 16 + lrow;
            bfr[q] = *(bf16x8*)&lds[cur][1][row * 32 + 8 * (kc ^ swz)];
        }
#pragma unroll
        for (int m = 0; m < 4; ++m)
#pragma unroll
            for (int q = 0; q < 4; ++q)
                acc[m][q] = __builtin_amdgcn_mfma_f32_16x16x32_bf16(af[m], bfr[q], acc[m][q], 0, 0, 0);

        if (kt < 6) {
            asm volatile("s_waitcnt vmcnt(4)" ::: "memory");
        } else {
            asm volatile("s_waitcnt vmcnt(0)" ::: "memory");
        }
        __builtin_amdgcn_s_barrier();
        cur = (cur + 1 == 3) ? 0 : cur + 1;
    }
#undef STAGE
#undef GLDS

    // ---- epilogue: wave-private LDS transpose -> fully-coalesced NT dwordx4 ----
    float* sl = (float*)&lds[0][0][0] + wid * 2048;
#pragma unroll
    for (int h = 0; h < 2; ++h) {
#pragma unroll
        for (int m2 = 0; m2 < 2; ++m2) {
#pragma unroll
            for (int q = 0; q < 4; ++q) {
#pragma unroll
                for (int r = 0; r < 4; ++r) {
                    int i_loc = m2 * 16 + 4 * kc + r;
                    int n_swz = (q * 16 + lrow) ^ (((i_loc >> 2) & 3) << 4);
                    sl[i_loc * 64 + n_swz] = acc[2 * h + m2][q][r];
                }
            }
        }
#pragma unroll
        for (int j = 0; j < 8; ++j) {
            int i_loc = j * 4 + kc;
            int nb    = lrow * 4;
            int n_swz = nb ^ (((i_loc >> 2) & 3) << 4);
            f32x4 v  = *(f32x4*)&sl[i_loc * 64 + n_swz];
            int gi = i0 + wr * 64 + h * 32 + i_loc;
            int gn = n0 + wc * 64 + nb;
            f32x4 pv = *(const f32x4*)&para[(size_t)gi * HWW + gn];
            f32x4 o;
            o[0] = fmaxf(v[0] * pv[0], 0.f);
            o[1] = fmaxf(v[1] * pv[1], 0.f);
            o[2] = fmaxf(v[2] * pv[2], 0.f);
            o[3] = fmaxf(v[3] * pv[3], 0.f);
            __builtin_nontemporal_store(o, (f32x4*)&out[((size_t)b * CC + gi) * HWW + gn]);
        }
    }
}

// ================= FALLBACK (fp32 path, used if ws too small) =================

__global__ __launch_bounds__(256) void avgpool_kernel(const float* __restrict__ x,
                                                      float* __restrict__ c_adj) {
    int bc = blockIdx.x;
    const float4* p4 = (const float4*)(x + (size_t)bc * HWW);
    int t = threadIdx.x;
    float sum = 0.f;
#pragma unroll
    for (int m = 0; m < 4; ++m) {
        float4 v = p4[t + 256 * m];
        sum += v.x + v.y + v.z + v.w;
    }
#pragma unroll
    for (int off = 32; off > 0; off >>= 1)
        sum += __shfl_down(sum, off, 64);
    __shared__ float partial[4];
    int wid = t >> 6, lane = t & 63;
    if (lane == 0) partial[wid] = sum;
    __syncthreads();
    if (t == 0)
        c_adj[bc] = (partial[0] + partial[1] + partial[2] + partial[3]) * (1.0f / HWW);
}

__global__ __launch_bounds__(256) void weight_kernel(const float* __restrict__ c_adj,
                                                     const float* __restrict__ adj,
                                                     float* __restrict__ w) {
    int idx = blockIdx.x * 256 + threadIdx.x;
    int b = idx >> 16, rem = idx & 65535, i = rem >> 8, j = rem & 255;
    float d = c_adj[b * CC + j] - c_adj[b * CC + i];
    float tt = expf(-fabsf(d));
    w[idx] = adj[i * CC + j] * 2.f * tt / (1.f + tt);
}

#define BM 64
#define BN 64
#define BK 16
__global__ __launch_bounds__(256) void gemm_kernel(const float* __restrict__ w,
                                                   const float* __restrict__ x,
                                                   const float* __restrict__ para,
                                                   float* __restrict__ out) {
    int b = blockIdx.z, i0 = blockIdx.y * BM, n0 = blockIdx.x * BN;
    const float* wB = w + (size_t)b * CC * CC;
    const float* xB = x + (size_t)b * CC * HWW;
    float* outB = out + (size_t)b * CC * HWW;
    __shared__ float wT[BK][68];
    __shared__ float xS[BK][BN];
    int t = threadIdx.x, tr = t >> 4, tc = t & 15;
    float acc[4][4] = {};
    for (int k0 = 0; k0 < CC; k0 += BK) {
        {
            int i = t >> 2, kq = (t & 3) * 4;
            float4 v = *(const float4*)&wB[(size_t)(i0 + i) * CC + k0 + kq];
            wT[kq + 0][i] = v.x; wT[kq + 1][i] = v.y; wT[kq + 2][i] = v.z; wT[kq + 3][i] = v.w;
        }
        {
            int k = t >> 4, nq = (t & 15) * 4;
            *(float4*)&xS[k][nq] = *(const float4*)&xB[(size_t)(k0 + k) * HWW + n0 + nq];
        }
        __syncthreads();
#pragma unroll
        for (int k = 0; k < BK; ++k) {
            float wv[4], xv[4];
            *(float4*)wv = *(const float4*)&wT[k][tr * 4];
            *(float4*)xv = *(const float4*)&xS[k][tc * 4];
#pragma unroll
            for (int r = 0; r < 4; ++r)
#pragma unroll
                for (int q = 0; q < 4; ++q)
                    acc[r][q] = fmaf(wv[r], xv[q], acc[r][q]);
        }
        __syncthreads();
    }
#pragma unroll
    for (int r = 0; r < 4; ++r) {
        int i = i0 + tr * 4 + r, n = n0 + tc * 4;
        float4 pv = *(const float4*)&para[(size_t)i * HWW + n];
        float4 o;
        o.x = fmaxf(acc[r][0] * pv.x, 0.f);
        o.y = fmaxf(acc[r][1] * pv.y, 0.f);
        o.z = fmaxf(acc[r][2] * pv.z, 0.f);
        o.w = fmaxf(acc[r][3] * pv.w, 0.f);
        *(float4*)&outB[(size_t)i * HWW + n] = o;
    }
}

// ================= launch =================

extern "C" void kernel_launch(void* const* d_in, const int* in_sizes, int n_in,
                              void* d_out, int out_size, void* d_ws, size_t ws_size,
                              hipStream_t stream) {
    const float* x    = (const float*)d_in[0];
    const float* adj  = (const float*)d_in[1];
    const float* para = (const float*)d_in[2];
    float* out = (float*)d_out;

    const size_t XT_BYTES = (size_t)BB * HWW * CC * 2;       // 67,108,864
    const size_t WB_BYTES = (size_t)BB * CC * CC * 2;        //  4,194,304
    const size_t PT_BYTES = (size_t)BB * 64 * CC * 4;        //  2,097,152
    const size_t REQ = XT_BYTES + WB_BYTES + PT_BYTES;

    if (ws_size >= REQ) {
        u16*   xT      = (u16*)d_ws;
        u16*   wbuf    = (u16*)((char*)d_ws + XT_BYTES);
        float* partial = (float*)((char*)d_ws + XT_BYTES + WB_BYTES);

        dim3 gA(HWW / 64, CC / 64, BB);
        pool_transpose_kernel<<<gA, 256, 0, stream>>>(x, xT, partial);
        reduce_weight_kernel<<<BB * 8, 256, 0, stream>>>(partial, adj, wbuf);
        dim3 gC(HWW / GBN, CC / GBM, BB);
        mfma_gemm_kernel<<<gC, 256, 0, stream>>>(wbuf, xT, para, out);
    } else {
        float* c_adj = (float*)d_ws;
        float* w     = (float*)d_ws + (BB * CC);
        avgpool_kernel<<<BB * CC, 256, 0, stream>>>(x, c_adj);
        weight_kernel<<<(BB * CC * CC) / 256, 256, 0, stream>>>(c_adj, adj, w);
        dim3 grid(HWW / BN, CC / BM, BB);
        gemm_kernel<<<grid, 256, 0, stream>>>(w, x, para, out);
    }
}